// Round 3
// baseline (275.308 us; speedup 1.0000x reference)
//
#include <hip/hip_runtime.h>
#include <stdint.h>

#define NTOK 16384   // B*S = 4*4096
#define DIN 512
#define DOUT 512
#define KE 8
#define BM 128
#define BN 128
#define BK 64

#define GATE_BLOCKS 2048           // 8 tokens/block
#define WCONV_BLOCKS 1024          // 2M elements / (256*8)

typedef unsigned short u16;
typedef u16 u16x8 __attribute__((ext_vector_type(8)));
typedef __bf16 bf16x8 __attribute__((ext_vector_type(8)));
typedef float f32x4 __attribute__((ext_vector_type(4)));

__device__ __forceinline__ u16 f2bf(float f) {
  union { float f; unsigned u; } v; v.f = f;
  unsigned r = v.u + 0x7FFFu + ((v.u >> 16) & 1u);   // RNE; inputs are finite
  return (u16)(r >> 16);
}

// async global->LDS, 16B per lane; LDS dest is wave-uniform base + lane*16
#define GLOAD_LDS16(gp, lp)                                              \
  __builtin_amdgcn_global_load_lds(                                     \
      (__attribute__((address_space(1))) void*)(gp),                    \
      (__attribute__((address_space(3))) void*)(lp), 16, 0, 0)

// ---------------------------------------------------------------------------
// Kernel 1 (merged prologue):
//  blocks [0, GATE_BLOCKS): gating softmax + x fp32->bf16 cast (8 tok/block)
//  blocks [GATE_BLOCKS, +WCONV_BLOCKS): expert-weight fp32->bf16 cast
// ---------------------------------------------------------------------------
__global__ __launch_bounds__(256) void prologue_kernel(
    const float* __restrict__ x, const float* __restrict__ mw,
    const float* __restrict__ mb, const float* __restrict__ ew,
    u16* __restrict__ xbf, u16* __restrict__ wbf, float* __restrict__ coeffs) {
  const int tid = threadIdx.x;

  if (blockIdx.x >= GATE_BLOCKS) {
    // ---- weight cast: 8 elements/thread ----
    const size_t i =
        ((size_t)(blockIdx.x - GATE_BLOCKS) * 256 + tid) * 8;
    const float4 a = *(const float4*)&ew[i];
    const float4 b = *(const float4*)&ew[i + 4];
    u16x8 p;
    p[0] = f2bf(a.x); p[1] = f2bf(a.y); p[2] = f2bf(a.z); p[3] = f2bf(a.w);
    p[4] = f2bf(b.x); p[5] = f2bf(b.y); p[6] = f2bf(b.z); p[7] = f2bf(b.w);
    *(u16x8*)&wbf[i] = p;
    return;
  }

  // ---- gating + x cast ----
  __shared__ __align__(16) float mwS[KE * DIN];   // 16 KB
  const int wave = tid >> 6, lane = tid & 63;

#pragma unroll
  for (int i = 0; i < 4; ++i) {
    const int idx = (tid + i * 256) * 4;
    *(float4*)&mwS[idx] = *(const float4*)&mw[idx];
  }
  float mbr[KE];
#pragma unroll
  for (int k = 0; k < KE; ++k) mbr[k] = mb[k];
  __syncthreads();

#pragma unroll
  for (int t = 0; t < 2; ++t) {
    const int tok = blockIdx.x * 8 + wave * 2 + t;
    const float* xr = x + (size_t)tok * DIN + lane * 8;
    const float4 xa = *(const float4*)xr;
    const float4 xb = *(const float4*)(xr + 4);

    u16x8 p;
    p[0] = f2bf(xa.x); p[1] = f2bf(xa.y); p[2] = f2bf(xa.z); p[3] = f2bf(xa.w);
    p[4] = f2bf(xb.x); p[5] = f2bf(xb.y); p[6] = f2bf(xb.z); p[7] = f2bf(xb.w);
    *(u16x8*)(xbf + (size_t)tok * DIN + lane * 8) = p;

    float lg[KE];
#pragma unroll
    for (int k = 0; k < KE; ++k) {
      const float* wr = &mwS[k * DIN + lane * 8];
      const float4 w0 = *(const float4*)wr;
      const float4 w1 = *(const float4*)(wr + 4);
      lg[k] = xa.x * w0.x + xa.y * w0.y + xa.z * w0.z + xa.w * w0.w +
              xb.x * w1.x + xb.y * w1.y + xb.z * w1.z + xb.w * w1.w;
    }
#pragma unroll
    for (int off = 32; off; off >>= 1)
#pragma unroll
      for (int k = 0; k < KE; ++k) lg[k] += __shfl_xor(lg[k], off);

#pragma unroll
    for (int k = 0; k < KE; ++k) lg[k] += mbr[k];
    float mx = lg[0];
#pragma unroll
    for (int k = 1; k < KE; ++k) mx = fmaxf(mx, lg[k]);
    float s = 0.f;
#pragma unroll
    for (int k = 0; k < KE; ++k) { lg[k] = __expf(lg[k] - mx); s += lg[k]; }
    const float inv = 1.f / s;
    if (lane == 0) {
      float* cp = coeffs + (size_t)tok * KE;
      float4 c0, c1;
      c0.x = lg[0] * inv; c0.y = lg[1] * inv; c0.z = lg[2] * inv; c0.w = lg[3] * inv;
      c1.x = lg[4] * inv; c1.y = lg[5] * inv; c1.z = lg[6] * inv; c1.w = lg[7] * inv;
      *(float4*)cp = c0;
      *(float4*)(cp + 4) = c1;
    }
  }
}

// ---------------------------------------------------------------------------
// Kernel 2: main MoE GEMM, BM=BN=128, BK=64, 2 blocks/CU.
// - XCD swizzle: XCD (b&7) owns 16 contiguous m-blocks (A set 2 MB + active
//   expert B slice ~1 MB stays L2-resident).
// - XOR-swizzled LDS tiles (16B granularity): slot s of row r holds global
//   chunk s^(r&7). global_load_lds writes are lane-contiguous (required);
//   fragment reads at slot = chunk^(row&7) touch all 32 banks per 8 lanes
//   (residual 2-way aliasing is free, m136).
// - 4 waves x (4x4) 16x16x32 bf16 frags = 0.5 ds_read_b128 per MFMA.
// ---------------------------------------------------------------------------
__global__ __launch_bounds__(256, 2) void moe_gemm_kernel(
    const u16* __restrict__ xbf, const u16* __restrict__ wbf,
    const float* __restrict__ coeffs, const float* __restrict__ ebias,
    float* __restrict__ out) {
  __shared__ __align__(16) u16 As[BM * BK];     // 16 KB [m][k] swizzled
  __shared__ __align__(16) u16 Bs[BN * BK];     // 16 KB [o][k] swizzled
  __shared__ __align__(16) float Cs[BM * KE];   // 4 KB coeffs tile
  __shared__ __align__(16) float BiS[KE * BN];  // 4 KB bias tile [e][o]

  const int tid = threadIdx.x;
  const int wave = tid >> 6, lane = tid & 63;

  // XCD swizzle: b&7 = xcd, s = intra-XCD sequence. 128 m-blocks total ->
  // 16 per XCD; n covers all 4 n-blocks.
  const int b = blockIdx.x;
  const int xcd = b & 7, s = b >> 3;
  const int m0 = (xcd * 16 + (s & 15)) * BM;
  const int n0 = (s >> 4) * BN;

  const int wm = (wave >> 1) * 64;   // wave's row offset: {0,64}
  const int wn = (wave & 1) * 64;    // wave's col offset: {0,64}

  // stage coeffs (128x8 fp32) and bias (8x128 fp32): one float4 per thread
  ((float4*)Cs)[tid] = ((const float4*)(coeffs + (size_t)m0 * KE))[tid];
  {
    const int k = tid >> 5, c = (tid & 31) * 4;
    *(float4*)&BiS[k * BN + c] = *(const float4*)&ebias[k * DOUT + n0 + c];
  }

  // staging: GLOAD chunk ci = wave*4+j covers tile rows ci*8..ci*8+7.
  // lane -> row lrow = lane>>3; SOURCE column chunk is XOR-swizzled so that
  // LDS slot s of row r ends up holding global chunk s^(r&7).
  const int lrow = lane >> 3;
  const int scol = ((lane & 7) ^ lrow) * 8;
  const u16* aBase = xbf + (size_t)(m0 + wave * 32 + lrow) * DIN + scol;

  f32x4 acc[4][4] = {};

  const int frow = lane & 15;
  const int fsel = lane >> 4;        // frag chunk sub-index
  const int fxor = lane & 7;         // row&7 for frag rows (wm,mi*16 mult of 8)

  for (int e = 0; e < KE; ++e) {
    f32x4 part[4][4] = {};
    const u16* bBase = wbf + (size_t)e * DOUT * DIN +
                       (size_t)(n0 + wave * 32 + lrow) * DIN + scol;

    for (int t = 0; t < DIN / BK; ++t) {   // 8 BK-tiles per expert
      const int i0 = t * BK;
      __syncthreads();   // prior tile's LDS reads done
#pragma unroll
      for (int j = 0; j < 4; ++j) {
        GLOAD_LDS16(aBase + (size_t)(j * 8) * DIN + i0, &As[(wave * 4 + j) * 512]);
        GLOAD_LDS16(bBase + (size_t)(j * 8) * DIN + i0, &Bs[(wave * 4 + j) * 512]);
      }
      __syncthreads();   // barrier drains vmcnt -> LDS valid
#pragma unroll
      for (int ks = 0; ks < 2; ++ks) {
        const int slot = (ks * 4 + fsel) ^ fxor;   // pure lane fn (rows mult 8)
        bf16x8 af[4], bfv[4];
#pragma unroll
        for (int mi = 0; mi < 4; ++mi)
          af[mi] = *(const bf16x8*)&As[(wm + mi * 16 + frow) * BK + slot * 8];
#pragma unroll
        for (int ni = 0; ni < 4; ++ni)
          bfv[ni] = *(const bf16x8*)&Bs[(wn + ni * 16 + frow) * BK + slot * 8];
#pragma unroll
        for (int mi = 0; mi < 4; ++mi)
#pragma unroll
          for (int ni = 0; ni < 4; ++ni)
            part[mi][ni] = __builtin_amdgcn_mfma_f32_16x16x32_bf16(
                af[mi], bfv[ni], part[mi][ni], 0, 0, 0);
      }
    }

    // fold expert partial into final acc, scaled by c[row, e] (fp32)
    // C/D layout (m89/m91): col = lane&15, row = (lane>>4)*4 + reg
#pragma unroll
    for (int mi = 0; mi < 4; ++mi) {
      const int rb = wm + mi * 16 + (lane >> 4) * 4;
#pragma unroll
      for (int j = 0; j < 4; ++j) {
        const float cf = Cs[(rb + j) * KE + e];
#pragma unroll
        for (int ni = 0; ni < 4; ++ni) acc[mi][ni][j] += cf * part[mi][ni][j];
      }
    }
  }

  // epilogue: rank-8 bias update + store
  float bcol[4][KE];
#pragma unroll
  for (int ni = 0; ni < 4; ++ni) {
    const int col = wn + ni * 16 + frow;
#pragma unroll
    for (int k = 0; k < KE; ++k) bcol[ni][k] = BiS[k * BN + col];
  }
#pragma unroll
  for (int mi = 0; mi < 4; ++mi) {
    const int rb = wm + mi * 16 + (lane >> 4) * 4;
#pragma unroll
    for (int j = 0; j < 4; ++j) {
      const int row = rb + j;
      float cr[KE];
#pragma unroll
      for (int k = 0; k < KE; ++k) cr[k] = Cs[row * KE + k];
#pragma unroll
      for (int ni = 0; ni < 4; ++ni) {
        float bias = 0.f;
#pragma unroll
        for (int k = 0; k < KE; ++k) bias += cr[k] * bcol[ni][k];
        const int col = wn + ni * 16 + frow;
        out[(size_t)(m0 + row) * DOUT + n0 + col] = acc[mi][ni][j] + bias;
      }
    }
  }
}

// ---------------------------------------------------------------------------
extern "C" void kernel_launch(void* const* d_in, const int* in_sizes, int n_in,
                              void* d_out, int out_size, void* d_ws,
                              size_t ws_size, hipStream_t stream) {
  (void)in_sizes; (void)n_in; (void)out_size; (void)ws_size;
  const float* x  = (const float*)d_in[0];   // [4,4096,512]
  const float* ew = (const float*)d_in[1];   // [8,512,512]
  const float* eb = (const float*)d_in[2];   // [8,512]
  const float* mw = (const float*)d_in[3];   // [8,512]
  const float* mb = (const float*)d_in[4];   // [8]
  float* out = (float*)d_out;                // [4,4096,512]

  // workspace layout: xbf 16 MB | wbf 4 MB | coeffs 0.5 MB  (~20.5 MB)
  u16* xbf = (u16*)d_ws;
  u16* wbf = (u16*)((char*)d_ws + (size_t)NTOK * DIN * 2);
  float* coeffs =
      (float*)((char*)d_ws + (size_t)NTOK * DIN * 2 + (size_t)KE * DOUT * DIN * 2);

  hipLaunchKernelGGL(prologue_kernel, dim3(GATE_BLOCKS + WCONV_BLOCKS),
                     dim3(256), 0, stream, x, mw, mb, ew, xbf, wbf, coeffs);
  hipLaunchKernelGGL(moe_gemm_kernel, dim3((NTOK / BM) * (DOUT / BN)), dim3(256),
                     0, stream, xbf, wbf, coeffs, eb, out);
}

// Round 4
// 189.425 us; speedup vs baseline: 1.4534x; 1.4534x over previous
//
#include <hip/hip_runtime.h>
#include <stdint.h>

#define NTOK 16384   // B*S = 4*4096
#define DIN 512
#define DOUT 512
#define KE 8
#define BM 64
#define BN 128
#define BK 64

#define GATE_BLOCKS 2048           // 8 tokens/block
#define WCONV_BLOCKS 1024          // 2M elements / (256*8)

typedef unsigned short u16;
typedef u16 u16x8 __attribute__((ext_vector_type(8)));
typedef __bf16 bf16x8 __attribute__((ext_vector_type(8)));
typedef float f32x4 __attribute__((ext_vector_type(4)));

__device__ __forceinline__ u16 f2bf(float f) {
  union { float f; unsigned u; } v; v.f = f;
  unsigned r = v.u + 0x7FFFu + ((v.u >> 16) & 1u);   // RNE; inputs are finite
  return (u16)(r >> 16);
}

// async global->LDS, 16B per lane; LDS dest is wave-uniform base + lane*16
#define GLOAD_LDS16(gp, lp)                                              \
  __builtin_amdgcn_global_load_lds(                                     \
      (__attribute__((address_space(1))) void*)(gp),                    \
      (__attribute__((address_space(3))) void*)(lp), 16, 0, 0)

// ---------------------------------------------------------------------------
// Kernel 1 (merged prologue):
//  blocks [0, GATE_BLOCKS): gating softmax + x fp32->bf16 cast (8 tok/block)
//  blocks [GATE_BLOCKS, +WCONV_BLOCKS): expert-weight fp32->bf16 cast
// ---------------------------------------------------------------------------
__global__ __launch_bounds__(256) void prologue_kernel(
    const float* __restrict__ x, const float* __restrict__ mw,
    const float* __restrict__ mb, const float* __restrict__ ew,
    u16* __restrict__ xbf, u16* __restrict__ wbf, float* __restrict__ coeffs) {
  const int tid = threadIdx.x;

  if (blockIdx.x >= GATE_BLOCKS) {
    // ---- weight cast: 8 elements/thread ----
    const size_t i =
        ((size_t)(blockIdx.x - GATE_BLOCKS) * 256 + tid) * 8;
    const float4 a = *(const float4*)&ew[i];
    const float4 b = *(const float4*)&ew[i + 4];
    u16x8 p;
    p[0] = f2bf(a.x); p[1] = f2bf(a.y); p[2] = f2bf(a.z); p[3] = f2bf(a.w);
    p[4] = f2bf(b.x); p[5] = f2bf(b.y); p[6] = f2bf(b.z); p[7] = f2bf(b.w);
    *(u16x8*)&wbf[i] = p;
    return;
  }

  // ---- gating + x cast ----
  __shared__ __align__(16) float mwS[KE * DIN];   // 16 KB
  const int wave = tid >> 6, lane = tid & 63;

#pragma unroll
  for (int i = 0; i < 4; ++i) {
    const int idx = (tid + i * 256) * 4;
    *(float4*)&mwS[idx] = *(const float4*)&mw[idx];
  }
  float mbr[KE];
#pragma unroll
  for (int k = 0; k < KE; ++k) mbr[k] = mb[k];
  __syncthreads();

#pragma unroll
  for (int t = 0; t < 2; ++t) {
    const int tok = blockIdx.x * 8 + wave * 2 + t;
    const float* xr = x + (size_t)tok * DIN + lane * 8;
    const float4 xa = *(const float4*)xr;
    const float4 xb = *(const float4*)(xr + 4);

    u16x8 p;
    p[0] = f2bf(xa.x); p[1] = f2bf(xa.y); p[2] = f2bf(xa.z); p[3] = f2bf(xa.w);
    p[4] = f2bf(xb.x); p[5] = f2bf(xb.y); p[6] = f2bf(xb.z); p[7] = f2bf(xb.w);
    *(u16x8*)(xbf + (size_t)tok * DIN + lane * 8) = p;

    float lg[KE];
#pragma unroll
    for (int k = 0; k < KE; ++k) {
      const float* wr = &mwS[k * DIN + lane * 8];
      const float4 w0 = *(const float4*)wr;
      const float4 w1 = *(const float4*)(wr + 4);
      lg[k] = xa.x * w0.x + xa.y * w0.y + xa.z * w0.z + xa.w * w0.w +
              xb.x * w1.x + xb.y * w1.y + xb.z * w1.z + xb.w * w1.w;
    }
#pragma unroll
    for (int off = 32; off; off >>= 1)
#pragma unroll
      for (int k = 0; k < KE; ++k) lg[k] += __shfl_xor(lg[k], off);

#pragma unroll
    for (int k = 0; k < KE; ++k) lg[k] += mbr[k];
    float mx = lg[0];
#pragma unroll
    for (int k = 1; k < KE; ++k) mx = fmaxf(mx, lg[k]);
    float s = 0.f;
#pragma unroll
    for (int k = 0; k < KE; ++k) { lg[k] = __expf(lg[k] - mx); s += lg[k]; }
    const float inv = 1.f / s;
    if (lane == 0) {
      float* cp = coeffs + (size_t)tok * KE;
      float4 c0, c1;
      c0.x = lg[0] * inv; c0.y = lg[1] * inv; c0.z = lg[2] * inv; c0.w = lg[3] * inv;
      c1.x = lg[4] * inv; c1.y = lg[5] * inv; c1.z = lg[6] * inv; c1.w = lg[7] * inv;
      *(float4*)cp = c0;
      *(float4*)(cp + 4) = c1;
    }
  }
}

// ---------------------------------------------------------------------------
// Kernel 2: main MoE GEMM. BM=64 BN=128 BK=64, 4 blocks/CU (R2 shape: both
// accumulator sets = 64 regs total -> VGPR 64, NO spill; the 128x128 variant
// spilled acc[] to scratch: 255 MB WRITE_SIZE, R1/R3 regression).
// - XCD swizzle: XCD (b&7) owns 32 contiguous m-blocks -> A re-reads and
//   active expert B slice stay L2-resident (FETCH 52 MB, R2-verified).
// - XOR-swizzled LDS (16B grain, R3-correctness-verified): LDS slot s of row
//   r holds global chunk s^(r&7); frag reads at slot=chunk^(row&7) hit all
//   32 banks per 8 lanes, residual 2-way aliasing free (m136).
// ---------------------------------------------------------------------------
__global__ __launch_bounds__(256, 4) void moe_gemm_kernel(
    const u16* __restrict__ xbf, const u16* __restrict__ wbf,
    const float* __restrict__ coeffs, const float* __restrict__ ebias,
    float* __restrict__ out) {
  __shared__ __align__(16) u16 As[BM * BK];     // 8 KB  [m][k] swizzled
  __shared__ __align__(16) u16 Bs[BN * BK];     // 16 KB [o][k] swizzled
  __shared__ __align__(16) float Cs[BM * KE];   // 2 KB coeffs tile
  __shared__ __align__(16) float BiS[KE * BN];  // 4 KB bias tile [e][o]

  const int tid = threadIdx.x;
  const int wave = tid >> 6, lane = tid & 63;

  // XCD swizzle: b&7 = xcd (round-robin dispatch), s = intra-XCD sequence.
  const int b = blockIdx.x;
  const int xcd = b & 7, s = b >> 3;
  const int m0 = (xcd * 32 + (s & 31)) * BM;
  const int n0 = (s >> 5) * BN;

  const int wm = (wave >> 1) * 32;   // wave's row offset: {0,32}
  const int wn = (wave & 1) * 64;    // wave's col offset: {0,64}

  // stage coeffs (64x8 fp32, threads 0-127) and bias (8x128 fp32)
  if (tid < 128) ((float4*)Cs)[tid] = ((const float4*)(coeffs + (size_t)m0 * KE))[tid];
  {
    const int k = tid >> 5, c = (tid & 31) * 4;
    *(float4*)&BiS[k * BN + c] = *(const float4*)&ebias[k * DOUT + n0 + c];
  }

  // staging: each GLOAD covers 8 rows x 64 cols (1 KB). lane -> row (lane>>3);
  // SOURCE col chunk is XOR-swizzled so LDS slot s of row r = global chunk
  // s^(r&7). A: 8 chunks (2/wave, rows wave*16+j*8+lrow); B: 16 (4/wave).
  const int lrow = lane >> 3;
  const int scol = ((lane & 7) ^ lrow) * 8;
  const u16* aBase = xbf + (size_t)(m0 + wave * 16 + lrow) * DIN + scol;

  f32x4 acc[2][4] = {};

  const int frow = lane & 15;
  const int fsel = lane >> 4;        // frag chunk sub-index
  const int fxor = lane & 7;         // row&7 for frag rows (frow&7 == lane&7)

  for (int e = 0; e < KE; ++e) {
    f32x4 part[2][4] = {};
    const u16* bBase = wbf + (size_t)e * DOUT * DIN +
                       (size_t)(n0 + wave * 32 + lrow) * DIN + scol;

    for (int t = 0; t < DIN / BK; ++t) {   // 8 BK-tiles per expert
      const int i0 = t * BK;
      __syncthreads();   // prior tile's LDS reads done
#pragma unroll
      for (int j = 0; j < 2; ++j)
        GLOAD_LDS16(aBase + (size_t)(j * 8) * DIN + i0, &As[(wave * 2 + j) * 512]);
#pragma unroll
      for (int j = 0; j < 4; ++j)
        GLOAD_LDS16(bBase + (size_t)(j * 8) * DIN + i0, &Bs[(wave * 4 + j) * 512]);
      __syncthreads();   // barrier drains vmcnt -> LDS valid
#pragma unroll
      for (int ks = 0; ks < 2; ++ks) {
        const int slot = (ks * 4 + fsel) ^ fxor;   // pure lane fn (rows mult 8)
        bf16x8 af[2], bfv[4];
#pragma unroll
        for (int mi = 0; mi < 2; ++mi)
          af[mi] = *(const bf16x8*)&As[(wm + mi * 16 + frow) * BK + slot * 8];
#pragma unroll
        for (int ni = 0; ni < 4; ++ni)
          bfv[ni] = *(const bf16x8*)&Bs[(wn + ni * 16 + frow) * BK + slot * 8];
#pragma unroll
        for (int mi = 0; mi < 2; ++mi)
#pragma unroll
          for (int ni = 0; ni < 4; ++ni)
            part[mi][ni] = __builtin_amdgcn_mfma_f32_16x16x32_bf16(
                af[mi], bfv[ni], part[mi][ni], 0, 0, 0);
      }
    }

    // fold expert partial into final acc, scaled by c[row, e] (fp32)
    // C/D layout (m89/m91): col = lane&15, row = (lane>>4)*4 + reg
#pragma unroll
    for (int mi = 0; mi < 2; ++mi) {
      const int rb = wm + mi * 16 + (lane >> 4) * 4;
#pragma unroll
      for (int j = 0; j < 4; ++j) {
        const float cf = Cs[(rb + j) * KE + e];
#pragma unroll
        for (int ni = 0; ni < 4; ++ni) acc[mi][ni][j] += cf * part[mi][ni][j];
      }
    }
  }

  // epilogue: rank-8 bias update + store
  float bcol[4][KE];
#pragma unroll
  for (int ni = 0; ni < 4; ++ni) {
    const int col = wn + ni * 16 + frow;
#pragma unroll
    for (int k = 0; k < KE; ++k) bcol[ni][k] = BiS[k * BN + col];
  }
#pragma unroll
  for (int mi = 0; mi < 2; ++mi) {
    const int rb = wm + mi * 16 + (lane >> 4) * 4;
#pragma unroll
    for (int j = 0; j < 4; ++j) {
      const int row = rb + j;
      float cr[KE];
#pragma unroll
      for (int k = 0; k < KE; ++k) cr[k] = Cs[row * KE + k];
#pragma unroll
      for (int ni = 0; ni < 4; ++ni) {
        float bias = 0.f;
#pragma unroll
        for (int k = 0; k < KE; ++k) bias += cr[k] * bcol[ni][k];
        const int col = wn + ni * 16 + frow;
        out[(size_t)(m0 + row) * DOUT + n0 + col] = acc[mi][ni][j] + bias;
      }
    }
  }
}

// ---------------------------------------------------------------------------
extern "C" void kernel_launch(void* const* d_in, const int* in_sizes, int n_in,
                              void* d_out, int out_size, void* d_ws,
                              size_t ws_size, hipStream_t stream) {
  (void)in_sizes; (void)n_in; (void)out_size; (void)ws_size;
  const float* x  = (const float*)d_in[0];   // [4,4096,512]
  const float* ew = (const float*)d_in[1];   // [8,512,512]
  const float* eb = (const float*)d_in[2];   // [8,512]
  const float* mw = (const float*)d_in[3];   // [8,512]
  const float* mb = (const float*)d_in[4];   // [8]
  float* out = (float*)d_out;                // [4,4096,512]

  // workspace layout: xbf 16 MB | wbf 4 MB | coeffs 0.5 MB  (~20.5 MB)
  u16* xbf = (u16*)d_ws;
  u16* wbf = (u16*)((char*)d_ws + (size_t)NTOK * DIN * 2);
  float* coeffs =
      (float*)((char*)d_ws + (size_t)NTOK * DIN * 2 + (size_t)KE * DOUT * DIN * 2);

  hipLaunchKernelGGL(prologue_kernel, dim3(GATE_BLOCKS + WCONV_BLOCKS),
                     dim3(256), 0, stream, x, mw, mb, ew, xbf, wbf, coeffs);
  hipLaunchKernelGGL(moe_gemm_kernel, dim3((NTOK / BM) * (DOUT / BN)), dim3(256),
                     0, stream, xbf, wbf, coeffs, eb, out);
}